// Round 1
// baseline (148.126 us; speedup 1.0000x reference)
//
#include <hip/hip_runtime.h>

// LocallyConnected1d via bf16 MFMA: out[b,o,l] = sum_{i,k} x[b,i,l+k-4]*w[i,o,k,l] + bias[o,l]
// 512 per-l GEMMs (M=b=64, N=o (8 real, 8 zero-padded), K=576 k-major).
//
// R9: de-serialize the HBM stream (R8: 1.7 TB/s, latency-bound at 18 vmcnt(0)
// barrier drains).
//  * BAR(): lgkmcnt(0)-only raw s_barrier. __syncthreads drains vmcnt(0) per
//    step, killing the 3-slot weight ring; raw barrier + compiler's natural
//    counted vmcnt keeps weight loads in flight across all 18 barriers.
//    LDS safety: writers drain lgkm pre-barrier; readers' ds_reads retire
//    before their MFMAs (pre-barrier); Bs parities alternate as before.
//  * STAGE_XS split (T14): x-half-1 global->reg issued after STEP(5) (64 VGPR
//    for 3 steps), pack+ds_write at the boundary behind counted vmcnt(6) --
//    the 196 KB/CU mid-kernel x load hides under STEPs 6-8 instead of
//    serializing between two barriers. Same split for half-0 in the prologue.
//  * Everything else identical to R8 (layouts, stager mapping, XCD swizzle).

#define CIN   64
#define COUT  64
#define SEQ   512
#define KS    9
#define LT    16
#define OT    8
#define LWIN  24
#define WSTR  (COUT*KS*SEQ)            // weight i-stride (floats)
#define XBS   40                       // Xs b-stride (ush): 32 i + 8 pad (5 granules, coprime 8)
#define XLW   (64*XBS)                 // Xs lw-stride = 2560 ush
#define XS_ELEMS (LWIN*XLW)            // 61440 ush = 120 KB
#define BOS   40                       // Bs o-stride (ush)
#define BLS   (OT*BOS + 8)             // Bs l-stride = 328 ush (41 granules, odd)
#define BSLOT (LT*BLS)                 // 5248 ush per buffer
#define ZOFF  (XS_ELEMS + 2*BSLOT)     // zero region for n>=8 B-frag reads
#define LDS_USH (ZOFF + 64)            // 72000 ush
#define LDS_BYTES (LDS_USH*2)          // 144000 B -> 1 block/CU
#define NSTEP 18                       // 2 i-halves x 9 k-taps

typedef __attribute__((ext_vector_type(8))) short bf16x8;
typedef __attribute__((ext_vector_type(4))) float f32x4;

__device__ __forceinline__ uint pack2bf(float a0, float a1) {
    uint u0 = __float_as_uint(a0) + 0x8000u;
    uint u1 = __float_as_uint(a1) + 0x8000u;
    return __builtin_amdgcn_perm(u1, u0, 0x07060302);  // (bf(a1)<<16)|bf(a0)
}

// Relaxed barrier: drain LDS only. Global loads (weight ring / x prefetch)
// stay in flight across it; compiler emits counted vmcnt at their register
// uses. Memory-clobber asm on both sides pins LDS ops to their side of the
// barrier (loads can't hoist above, stores can't sink below).
#define BAR() do {                                                           \
    asm volatile("s_waitcnt lgkmcnt(0)" ::: "memory");                       \
    __builtin_amdgcn_s_barrier();                                            \
    asm volatile("" ::: "memory");                                           \
} while (0)

__global__ __launch_bounds__(1024, 4)
void lc1d_mfma(const float* __restrict__ x, const float* __restrict__ w,
               const float* __restrict__ bias, float* __restrict__ out)
{
    extern __shared__ ushort lds[];
    ushort* Xs = lds;                    // [lw 0..23][b 0..63][ii 0..31]
    ushort* BsB = lds + XS_ELEMS;        // 2 x [l 0..15][o 0..7][kk 0..31]

    const int tid  = threadIdx.x;
    const int lane = tid & 63;
    const int wvid = tid >> 6;           // 0..15
    const int bt = wvid & 3;             // wave's b-tile (16 b)
    const int lg = wvid >> 2;            // wave's l-group (4 l)
    const int lt = blockIdx.x >> 3;      // 0..31
    const int os = blockIdx.x & 7;       // 0..7 == XCD id
    const int l0 = lt * LT;
    const int o0 = os * OT;

    // ---- weight stager mapping (tid < 512): 64-B-contiguous l spans ----
    const bool stager = (tid < 512);
    const int lf  = tid & 3;             // float4 within the 16-l span
    const int oo  = (tid >> 2) & 7;     // o
    const int ipp = (tid >> 5) & 15;     // i-pair within 32-i half

    const float* wbase = w + ((size_t)(2*ipp)*COUT + (o0 + oo))*(KS*SEQ) + l0 + lf*4;

    float4 rA[3], rB[3];                 // 3-slot ring, i-pair per slot
    float4 xv0[8], xv1[8];               // x-half prefetch (reg-staged)

    // step s: ih = s/9 (i-half), k = s%9 (tap)
    #define LOAD_RING(sl, s) if (stager && (s) < NSTEP) {                        \
        const int ih_ = (s) / 9, k_ = (s) - 9*ih_;                               \
        const float* p_ = wbase + (size_t)ih_*32*WSTR + k_*SEQ;                  \
        rA[sl] = *(const float4*)p_;                                             \
        rB[sl] = *(const float4*)(p_ + WSTR);                                    \
    }

    // transpose+cvt ring slot -> Bs parity (s&1): b32 of i-pair at [l][o][kk]
    #define WRITE_BS(sl, s) if (stager) {                                        \
        ushort* dst_ = BsB + ((s)&1)*BSLOT + oo*BOS + 2*ipp;                     \
        _Pragma("unroll")                                                        \
        for (int dl = 0; dl < 4; ++dl) {                                         \
            uint pk_ = pack2bf((&rA[sl].x)[dl], (&rB[sl].x)[dl]);                \
            *(uint*)(dst_ + (lf*4+dl)*BLS) = pk_;                                \
        }                                                                        \
    }

    // x half ih -> regs: xv0/xv1[it] = x[b, ih*32+2ip(+1), l0-4+qq*4 ..+3]
    #define STAGE_XS_LOAD(ih) {                                                  \
        const int qq  = tid & 7;                                                 \
        const int rp0 = tid >> 3;                                                \
        const bool act = (qq < 6) &&                                             \
                         !((lt == 0 && qq == 0) || (lt == 31 && qq == 5));       \
        _Pragma("unroll")                                                        \
        for (int it = 0; it < 8; ++it) {                                         \
            const int rp = rp0 + it*128;                                         \
            const int b_ = rp >> 4, ip_ = rp & 15;                               \
            const float* s0 = x + ((size_t)(b_*CIN) + (ih)*32 + 2*ip_)*SEQ       \
                                + (l0 - 4) + qq*4;                               \
            xv0[it] = make_float4(0.f,0.f,0.f,0.f);                              \
            xv1[it] = xv0[it];                                                   \
            if (act) {                                                           \
                xv0[it] = *(const float4*)s0;                                    \
                xv1[it] = *(const float4*)(s0 + SEQ);                            \
            }                                                                    \
        }                                                                        \
    }

    // pack + ds_write the prefetched half: Xs[lw][b][ii]
    #define STAGE_XS_WRITE() {                                                   \
        const int qq  = tid & 7;                                                 \
        const int rp0 = tid >> 3;                                                \
        if (qq < 6) {                                                            \
            _Pragma("unroll")                                                    \
            for (int it = 0; it < 8; ++it) {                                     \
                const int rp = rp0 + it*128;                                     \
                const int b_ = rp >> 4, ip_ = rp & 15;                           \
                ushort* d_ = Xs + b_*XBS + 2*ip_;                                \
                _Pragma("unroll")                                                \
                for (int dl = 0; dl < 4; ++dl)                                   \
                    *(uint*)(d_ + (qq*4+dl)*XLW) =                               \
                        pack2bf((&xv0[it].x)[dl], (&xv1[it].x)[dl]);             \
            }                                                                    \
        }                                                                        \
    }

    // MFMA lane constants
    const int aoff = (bt*16 + (lane & 15))*XBS + (lane >> 4)*8;
    const int boff = (lane & 15)*BOS + (lane >> 4)*8;
    const bool nhi = (lane & 15) >= 8;                 // dead o lanes -> zeros
    const ushort* zptr = lds + ZOFF + (lane >> 4)*8;   // shared (broadcast) zeros

    f32x4 acc[4];
    #pragma unroll
    for (int j = 0; j < 4; ++j) acc[j] = (f32x4)0.0f;

    #define DO_MFMA(s) {                                                         \
        const int k_ = (s) % 9;                                                  \
        const ushort* BsS = BsB + ((s)&1)*BSLOT;                                 \
        _Pragma("unroll")                                                        \
        for (int dl = 0; dl < 4; ++dl) {                                         \
            const int ll = lg*4 + dl;                                            \
            bf16x8 Af = *(const bf16x8*)(Xs + (ll + k_)*XLW + aoff);             \
            const ushort* Bp = nhi ? zptr : (BsS + ll*BLS + boff);               \
            bf16x8 Bf = *(const bf16x8*)Bp;                                      \
            acc[dl] = __builtin_amdgcn_mfma_f32_16x16x32_bf16(Af, Bf, acc[dl],   \
                                                              0, 0, 0);          \
        }                                                                        \
    }

    // one barrier per step: during step s, stagers fill Bs parity (s+1)&1.
    // BAR (not __syncthreads) so the ring's global loads pipeline across steps.
    #define STEP(s) {                                                            \
        if ((s) < NSTEP-1) WRITE_BS(((s)+1)%3, (s)+1)                            \
        LOAD_RING(((s)+1)%3, (s)+4)                                              \
        DO_MFMA(s)                                                               \
        BAR();                                                                   \
    }

    // ---- prologue ----
    STAGE_XS_LOAD(0)   // x loads issued first: longest pole of the prologue
    LOAD_RING(0, 0)
    LOAD_RING(1, 1)
    LOAD_RING(2, 2)
    if (tid < 64) lds[ZOFF + tid] = 0;
    STAGE_XS_WRITE()   // counted vmcnt: waits x loads, ring stays in flight
    WRITE_BS(0, 0)
    LOAD_RING(0, 3)
    BAR();             // Xs(ih0) + Bs(step0) + zero region ready

    STEP(0)  STEP(1)  STEP(2)  STEP(3)  STEP(4)
    STEP(5)

    STAGE_XS_LOAD(1)   // issue-early: completes under STEPs 6-8 (counted vmcnt)

    STEP(6)  STEP(7)  STEP(8)

    STAGE_XS_WRITE()   // all step-8 Xs reads retired at STEP(8)'s barrier
    BAR();

    STEP(9)  STEP(10) STEP(11) STEP(12) STEP(13)
    STEP(14) STEP(15) STEP(16) STEP(17)

    // ---- epilogue: C col = o' = lane&15 (store only o'<8), row = b_local ----
    if (!nhi) {
        const int og = o0 + (lane & 15);
        const int rb = (lane >> 4)*4;
        #pragma unroll
        for (int dl = 0; dl < 4; ++dl) {
            const int lgl = l0 + lg*4 + dl;
            const float bv = bias[og*SEQ + lgl];
            #pragma unroll
            for (int r = 0; r < 4; ++r) {
                const int bg = bt*16 + rb + r;
                out[((size_t)(bg*COUT + og))*SEQ + lgl] = acc[dl][r] + bv;
            }
        }
    }
}

extern "C" void kernel_launch(void* const* d_in, const int* in_sizes, int n_in,
                              void* d_out, int out_size, void* d_ws, size_t ws_size,
                              hipStream_t stream) {
    const float* x    = (const float*)d_in[0];
    const float* wgt  = (const float*)d_in[1];
    const float* bias = (const float*)d_in[2];
    float* out        = (float*)d_out;

    hipFuncSetAttribute((const void*)lc1d_mfma,
                        hipFuncAttributeMaxDynamicSharedMemorySize, LDS_BYTES);
    dim3 grid(256);   // blockIdx = lt*8 + os: os == XCD id; lt line-mates co-XCD
    lc1d_mfma<<<grid, 1024, LDS_BYTES, stream>>>(x, wgt, bias, out);
}

// Round 2
// 137.290 us; speedup vs baseline: 1.0789x; 1.0789x over previous
//
#include <hip/hip_runtime.h>

// LocallyConnected1d via bf16 MFMA: out[b,o,l] = sum_{i,k} x[b,i,l+k-4]*w[i,o,k,l] + bias[o,l]
// 512 per-l GEMMs (M=b=64, N=o (8 real, 8 zero-padded), K=576 k-major).
//
// R10 = R8 + relaxed barrier ONLY (R9 post-mortem: the x reg-prefetch spilled
// 52 B/thread to scratch -> +13.5 MB writes; revert it, keep the barrier fix).
//  * BAR(): lgkmcnt(0)-only raw s_barrier. __syncthreads drains vmcnt(0) at
//    every one of 18 barriers, reducing the 3-slot weight ring to per-step
//    HBM round-trips (R8: 2.5 us/step, 1.7 TB/s). With BAR(), ring loads
//    issued at step s are first waited (counted vmcnt, compiler-emitted) at
//    their WRITE_BS use at step s+3 -- the weight stream pipelines across
//    barriers. LDS safety: writers drain lgkmcnt(0) pre-barrier; consumer
//    ds_reads of step s retire before their MFMAs, which precede the barrier;
//    Bs parity buffers alternate exactly as in R8.
//  * STAGE_XS: R8's combined per-iteration load->pack->write (8 regs live,
//    48 VGPR total). Mid-kernel x re-stage stays latency-exposed (~1-2 us);
//    acceptable until the weight stream is fixed.
//  * Everything else identical to R8 (layouts, stager mapping, XCD swizzle).

#define CIN   64
#define COUT  64
#define SEQ   512
#define KS    9
#define LT    16
#define OT    8
#define LWIN  24
#define WSTR  (COUT*KS*SEQ)            // weight i-stride (floats)
#define XBS   40                       // Xs b-stride (ush): 32 i + 8 pad (5 granules, coprime 8)
#define XLW   (64*XBS)                 // Xs lw-stride = 2560 ush
#define XS_ELEMS (LWIN*XLW)            // 61440 ush = 120 KB
#define BOS   40                       // Bs o-stride (ush)
#define BLS   (OT*BOS + 8)             // Bs l-stride = 328 ush (41 granules, odd)
#define BSLOT (LT*BLS)                 // 5248 ush per buffer
#define ZOFF  (XS_ELEMS + 2*BSLOT)     // zero region for n>=8 B-frag reads
#define LDS_USH (ZOFF + 64)            // 72000 ush
#define LDS_BYTES (LDS_USH*2)          // 144000 B -> 1 block/CU
#define NSTEP 18                       // 2 i-halves x 9 k-taps

typedef __attribute__((ext_vector_type(8))) short bf16x8;
typedef __attribute__((ext_vector_type(4))) float f32x4;

__device__ __forceinline__ uint pack2bf(float a0, float a1) {
    uint u0 = __float_as_uint(a0) + 0x8000u;
    uint u1 = __float_as_uint(a1) + 0x8000u;
    return __builtin_amdgcn_perm(u1, u0, 0x07060302);  // (bf(a1)<<16)|bf(a0)
}

// Relaxed barrier: drain LDS only. Global loads (weight ring) stay in flight
// across it; the compiler emits counted vmcnt at their register uses.
// Memory-clobber asm on both sides pins LDS/global ops to their side.
#define BAR() do {                                                           \
    asm volatile("s_waitcnt lgkmcnt(0)" ::: "memory");                       \
    __builtin_amdgcn_s_barrier();                                            \
    asm volatile("" ::: "memory");                                           \
} while (0)

__global__ __launch_bounds__(1024, 4)
void lc1d_mfma(const float* __restrict__ x, const float* __restrict__ w,
               const float* __restrict__ bias, float* __restrict__ out)
{
    extern __shared__ ushort lds[];
    ushort* Xs = lds;                    // [lw 0..23][b 0..63][ii 0..31]
    ushort* BsB = lds + XS_ELEMS;        // 2 x [l 0..15][o 0..7][kk 0..31]

    const int tid  = threadIdx.x;
    const int lane = tid & 63;
    const int wvid = tid >> 6;           // 0..15
    const int bt = wvid & 3;             // wave's b-tile (16 b)
    const int lg = wvid >> 2;            // wave's l-group (4 l)
    const int lt = blockIdx.x >> 3;      // 0..31
    const int os = blockIdx.x & 7;       // 0..7 == XCD id
    const int l0 = lt * LT;
    const int o0 = os * OT;

    // ---- weight stager mapping (tid < 512): 64-B-contiguous l spans ----
    const bool stager = (tid < 512);
    const int lf  = tid & 3;             // float4 within the 16-l span
    const int oo  = (tid >> 2) & 7;      // o
    const int ipp = (tid >> 5) & 15;     // i-pair within 32-i half

    const float* wbase = w + ((size_t)(2*ipp)*COUT + (o0 + oo))*(KS*SEQ) + l0 + lf*4;

    float4 rA[3], rB[3];                 // 3-slot ring, i-pair per slot

    // step s: ih = s/9 (i-half), k = s%9 (tap)
    #define LOAD_RING(sl, s) if (stager && (s) < NSTEP) {                        \
        const int ih_ = (s) / 9, k_ = (s) - 9*ih_;                               \
        const float* p_ = wbase + (size_t)ih_*32*WSTR + k_*SEQ;                  \
        rA[sl] = *(const float4*)p_;                                             \
        rB[sl] = *(const float4*)(p_ + WSTR);                                    \
    }

    // transpose+cvt ring slot -> Bs parity (s&1): b32 of i-pair at [l][o][kk]
    #define WRITE_BS(sl, s) if (stager) {                                        \
        ushort* dst_ = BsB + ((s)&1)*BSLOT + oo*BOS + 2*ipp;                     \
        _Pragma("unroll")                                                        \
        for (int dl = 0; dl < 4; ++dl) {                                         \
            uint pk_ = pack2bf((&rA[sl].x)[dl], (&rB[sl].x)[dl]);                \
            *(uint*)(dst_ + (lf*4+dl)*BLS) = pk_;                                \
        }                                                                        \
    }

    // stage Xs for i-half ih: Xs[lw][b][ii] = bf16(x[b, ih*32+ii, l0-4+lw])
    // thread = (qq = l-quad 0..5 of 8, rp = (b, ii-pair)); pack ii-pairs -> b32.
    #define STAGE_XS(ih) {                                                       \
        const int qq  = tid & 7;                                                 \
        const int rp0 = tid >> 3;                                                \
        if (qq < 6) {                                                            \
            _Pragma("unroll")                                                    \
            for (int it = 0; it < 8; ++it) {                                     \
                const int rp = rp0 + it*128;                                     \
                const int b_ = rp >> 4, ip_ = rp & 15;                           \
                const float* s0 = x + ((size_t)(b_*CIN) + (ih)*32 + 2*ip_)*SEQ   \
                                    + (l0 - 4) + qq*4;                           \
                float4 v0 = make_float4(0.f,0.f,0.f,0.f), v1 = v0;               \
                if (!((lt == 0 && qq == 0) || (lt == 31 && qq == 5))) {          \
                    v0 = *(const float4*)s0;                                     \
                    v1 = *(const float4*)(s0 + SEQ);                             \
                }                                                                \
                ushort* d_ = Xs + b_*XBS + 2*ip_;                                \
                _Pragma("unroll")                                                \
                for (int dl = 0; dl < 4; ++dl)                                   \
                    *(uint*)(d_ + (qq*4+dl)*XLW) = pack2bf((&v0.x)[dl],          \
                                                           (&v1.x)[dl]);         \
            }                                                                    \
        }                                                                        \
    }

    // MFMA lane constants
    const int aoff = (bt*16 + (lane & 15))*XBS + (lane >> 4)*8;
    const int boff = (lane & 15)*BOS + (lane >> 4)*8;
    const bool nhi = (lane & 15) >= 8;                 // dead o lanes -> zeros
    const ushort* zptr = lds + ZOFF + (lane >> 4)*8;   // shared (broadcast) zeros

    f32x4 acc[4];
    #pragma unroll
    for (int j = 0; j < 4; ++j) acc[j] = (f32x4)0.0f;

    #define DO_MFMA(s) {                                                         \
        const int k_ = (s) % 9;                                                  \
        const ushort* BsS = BsB + ((s)&1)*BSLOT;                                 \
        _Pragma("unroll")                                                        \
        for (int dl = 0; dl < 4; ++dl) {                                         \
            const int ll = lg*4 + dl;                                            \
            bf16x8 Af = *(const bf16x8*)(Xs + (ll + k_)*XLW + aoff);             \
            const ushort* Bp = nhi ? zptr : (BsS + ll*BLS + boff);               \
            bf16x8 Bf = *(const bf16x8*)Bp;                                      \
            acc[dl] = __builtin_amdgcn_mfma_f32_16x16x32_bf16(Af, Bf, acc[dl],   \
                                                              0, 0, 0);          \
        }                                                                        \
    }

    // one barrier per step: during step s, stagers fill Bs parity (s+1)&1.
    // BAR (not __syncthreads) so the ring's global loads pipeline across steps.
    #define STEP(s) {                                                            \
        if ((s) < NSTEP-1) WRITE_BS(((s)+1)%3, (s)+1)                            \
        LOAD_RING(((s)+1)%3, (s)+4)                                              \
        DO_MFMA(s)                                                               \
        BAR();                                                                   \
    }

    // ---- prologue ----
    LOAD_RING(0, 0)
    LOAD_RING(1, 1)
    LOAD_RING(2, 2)
    if (tid < 64) lds[ZOFF + tid] = 0;
    STAGE_XS(0)
    WRITE_BS(0, 0)
    LOAD_RING(0, 3)
    BAR();             // Xs(ih0) + Bs(step0) + zero region ready

    STEP(0)  STEP(1)  STEP(2)  STEP(3)  STEP(4)
    STEP(5)  STEP(6)  STEP(7)  STEP(8)

    STAGE_XS(1)        // all step-8 Xs reads completed at STEP(8)'s barrier
    BAR();

    STEP(9)  STEP(10) STEP(11) STEP(12) STEP(13)
    STEP(14) STEP(15) STEP(16) STEP(17)

    // ---- epilogue: C col = o' = lane&15 (store only o'<8), row = b_local ----
    if (!nhi) {
        const int og = o0 + (lane & 15);
        const int rb = (lane >> 4)*4;
        #pragma unroll
        for (int dl = 0; dl < 4; ++dl) {
            const int lgl = l0 + lg*4 + dl;
            const float bv = bias[og*SEQ + lgl];
            #pragma unroll
            for (int r = 0; r < 4; ++r) {
                const int bg = bt*16 + rb + r;
                out[((size_t)(bg*COUT + og))*SEQ + lgl] = acc[dl][r] + bv;
            }
        }
    }
}

extern "C" void kernel_launch(void* const* d_in, const int* in_sizes, int n_in,
                              void* d_out, int out_size, void* d_ws, size_t ws_size,
                              hipStream_t stream) {
    const float* x    = (const float*)d_in[0];
    const float* wgt  = (const float*)d_in[1];
    const float* bias = (const float*)d_in[2];
    float* out        = (float*)d_out;

    hipFuncSetAttribute((const void*)lc1d_mfma,
                        hipFuncAttributeMaxDynamicSharedMemorySize, LDS_BYTES);
    dim3 grid(256);   // blockIdx = lt*8 + os: os == XCD id; lt line-mates co-XCD
    lc1d_mfma<<<grid, 1024, LDS_BYTES, stream>>>(x, wgt, bias, out);
}